// Round 7
// baseline (153.479 us; speedup 1.0000x reference)
//
#include <hip/hip_runtime.h>
#include <hip/hip_bf16.h>
#include <stdint.h>

#define NTOK 197
#define NPAD 224
#define BATCH 64
#define DMODEL 768
#define NHEAD 12
#define GHEAD 2
#define HRATIO 6
#define DHEAD 64
#define QKDIM 128
#define LNEPS 1e-5f
#define MROWS (NTOK * BATCH)   /* 12608 */
#define MPAD 12672             /* 99 * 128 */

using f32x4 = __attribute__((ext_vector_type(4))) float;
using s16x8 = __attribute__((ext_vector_type(8))) short;
using s16x4 = __attribute__((ext_vector_type(4))) short;

__device__ __forceinline__ short f2bf(float f) {
  unsigned int x = __float_as_uint(f);
  return (short)((x + 0x7fffu + ((x >> 16) & 1u)) >> 16);
}

__device__ __forceinline__ float bf2f(short s) {
  return __uint_as_float((unsigned)(unsigned short)s << 16);
}

__device__ __forceinline__ void gld16(void* lds, const void* g) {
  __builtin_amdgcn_global_load_lds(
      (const __attribute__((address_space(1))) unsigned int*)g,
      (__attribute__((address_space(3))) unsigned int*)lds, 16, 0, 0);
}

// ---------- fused casts: h->bf16, Wq|Wk|Wv concat->bf16, Wo->bf16 ----------
#define NB_H 4728    /* (12608*768/8)/256 */
#define NB_QKV 384   /* (1024*768/8)/256 */
#define NB_WO 288    /* (768*768/8)/256 */
__global__ __launch_bounds__(256)
void prep_kernel(const float* __restrict__ h, const float* __restrict__ Wq,
                 const float* __restrict__ Wk, const float* __restrict__ Wv,
                 const float* __restrict__ Wo, short* __restrict__ hb,
                 short* __restrict__ Wqkvb, short* __restrict__ Wob) {
  const int bb = blockIdx.x, t = threadIdx.x;
  const float* src;
  short* dst;
  if (bb < NB_H) {
    int idx = bb * 256 + t;
    src = h + (size_t)idx * 8;
    dst = hb + (size_t)idx * 8;
  } else if (bb < NB_H + NB_QKV) {
    int idx = (bb - NB_H) * 256 + t;
    int r = idx / 96, u = idx - r * 96;
    const float* s0 = (r < 128) ? Wq + (size_t)r * DMODEL
                    : (r < 256) ? Wk + (size_t)(r - 128) * DMODEL
                                : Wv + (size_t)(r - 256) * DMODEL;
    src = s0 + u * 8;
    dst = Wqkvb + (size_t)r * DMODEL + u * 8;
  } else {
    int idx = (bb - NB_H - NB_QKV) * 256 + t;
    src = Wo + (size_t)idx * 8;
    dst = Wob + (size_t)idx * 8;
  }
  float4 a = *(const float4*)src;
  float4 c = *(const float4*)(src + 4);
  s16x8 o;
  o[0] = f2bf(a.x); o[1] = f2bf(a.y); o[2] = f2bf(a.z); o[3] = f2bf(a.w);
  o[4] = f2bf(c.x); o[5] = f2bf(c.y); o[6] = f2bf(c.z); o[7] = f2bf(c.w);
  *(s16x8*)dst = o;
}

// ---------- bf16 NT GEMM, 128x128 tile, BK=32, 2-deep pipeline, XCD swz ----
__global__ __launch_bounds__(256)
void gemm_bt_kernel(const short* __restrict__ A, const short* __restrict__ W,
                    short* __restrict__ Cout, int M, int K, int NC) {
  __shared__ short As[3 * 128 * 32];   // 24 KB
  __shared__ short Ws[3 * 128 * 32];   // 24 KB
  const int tid = threadIdx.x;

  // XCD-bijective swizzle (m204)
  const int nwg = gridDim.x * gridDim.y;
  const int orig = blockIdx.y * gridDim.x + blockIdx.x;
  const int qq = nwg >> 3, rr = nwg & 7;
  const int xcd = orig & 7, sidx = orig >> 3;
  const int wg = (xcd < rr ? xcd * (qq + 1) : rr * (qq + 1) + (xcd - rr) * qq) + sidx;
  const int bn = (wg % gridDim.x) * 128;
  const int bm = (wg / gridDim.x) * 128;

  const int w = tid >> 6, l = tid & 63;
  const int wr = w >> 1, wc = w & 1;
  const int lm = l & 15, lh = l >> 4;

  const int srow = tid >> 2;
  const int schunk = (tid & 3) ^ ((tid >> 3) & 3);
  const short* Ag = A + (size_t)(bm + srow) * K + schunk * 8;
  const short* Wg = W + (size_t)(bn + srow) * K + schunk * 8;

  const int csw = lh ^ ((lm >> 1) & 3);
  f32x4 acc[4][4] = {};

#define STAGE(buf, kt)                                                     \
  do {                                                                     \
    gld16(As + (buf) * 4096 + tid * 8, Ag + (kt));                         \
    gld16(As + (buf) * 4096 + 2048 + tid * 8, Ag + (size_t)64 * K + (kt)); \
    gld16(Ws + (buf) * 4096 + tid * 8, Wg + (kt));                         \
    gld16(Ws + (buf) * 4096 + 2048 + tid * 8, Wg + (size_t)64 * K + (kt)); \
  } while (0)

  const int NK = K >> 5;  // 24
  STAGE(0, 0);
  STAGE(1, 32);
  for (int ki = 0; ki < NK; ++ki) {
    // retire only tile ki's 4 loads; tile ki+1 stays in flight across barrier
    if (ki + 1 < NK) asm volatile("s_waitcnt vmcnt(4)" ::: "memory");
    else             asm volatile("s_waitcnt vmcnt(0)" ::: "memory");
    __builtin_amdgcn_s_barrier();
    if (ki + 2 < NK) STAGE((ki + 2) % 3, (ki + 2) * 32);
    const int cur = ki % 3;
    const char* Ab = (const char*)(As + cur * 4096);
    const char* Bb = (const char*)(Ws + cur * 4096);
    s16x8 af[4], bf[4];
#pragma unroll
    for (int m = 0; m < 4; ++m)
      af[m] = *(const s16x8*)(Ab + (wr * 64 + m * 16 + lm) * 64 + csw * 16);
#pragma unroll
    for (int n = 0; n < 4; ++n)
      bf[n] = *(const s16x8*)(Bb + (wc * 64 + n * 16 + lm) * 64 + csw * 16);
#pragma unroll
    for (int m = 0; m < 4; ++m)
#pragma unroll
      for (int n = 0; n < 4; ++n)
        acc[m][n] = __builtin_amdgcn_mfma_f32_16x16x32_bf16(af[m], bf[n], acc[m][n], 0, 0, 0);
    // all waves must finish reading buf cur before iter ki+1 overwrites it
    asm volatile("s_waitcnt lgkmcnt(0)" ::: "memory");
    __builtin_amdgcn_s_barrier();
  }
#undef STAGE

#pragma unroll
  for (int m = 0; m < 4; ++m) {
#pragma unroll
    for (int r = 0; r < 4; ++r) {
      int row = bm + wr * 64 + m * 16 + lh * 4 + r;
      if (row < M) {
#pragma unroll
        for (int n = 0; n < 4; ++n) {
          int col = bn + wc * 64 + n * 16 + lm;
          Cout[(size_t)row * NC + col] = f2bf(acc[m][n][r]);
        }
      }
    }
  }
}

// ---------- fused packs: q(plain)/k(swizzled)/vT(plain) + packed mask mwp ---
__global__ __launch_bounds__(256)
void packall_kernel(const short* __restrict__ Cb, const float* __restrict__ masks,
                    const float* __restrict__ mproj, short* __restrict__ qp,
                    short* __restrict__ kp, short* __restrict__ vT,
                    float* __restrict__ mwp) {
  __shared__ short Vs[NPAD][DHEAD + 1];
  const int bb = blockIdx.x, t = threadIdx.x;
  if (bb < 256) {
    int b = bb >> 2, g = (bb >> 1) & 1, which = bb & 1;
    short* dst = (which ? kp : qp) + ((size_t)b * GHEAD + g) * NPAD * 64;
    int d = t & 63, iofs = t >> 6;
    for (int i0 = 0; i0 < NPAD; i0 += 4) {
      int i = i0 + iofs;
      short v = 0;
      if (i < NTOK)
        v = Cb[(size_t)(i * BATCH + b) * 1024 + which * QKDIM + g * DHEAD + d];
      int dd = which ? ((((d >> 3) ^ (i & 7)) << 3) | (d & 7)) : d;
      dst[i * 64 + dd] = v;
    }
  } else if (bb < 1024) {
    int vv = bb - 256;
    int b = vv / 12, n = vv - b * 12;
    int d = t & 63, iofs = t >> 6;
    for (int i0 = 0; i0 < NPAD; i0 += 4) {
      int i = i0 + iofs;
      short v = 0;
      if (i < NTOK)
        v = Cb[(size_t)(i * BATCH + b) * 1024 + 256 + n * DHEAD + d];
      Vs[i][d] = v;
    }
    __syncthreads();
    short* dst = vT + ((size_t)b * NHEAD + n) * DHEAD * NPAD;
    int sub = t & 63, dr = t >> 6;
    for (int d0 = 0; d0 < DHEAD; d0 += 4) {
      if (sub < 56) {
        int dd = d0 + dr, j0 = sub * 4;
        s16x4 o;
        o[0] = Vs[j0][dd]; o[1] = Vs[j0 + 1][dd];
        o[2] = Vs[j0 + 2][dd]; o[3] = Vs[j0 + 3][dd];
        *(s16x4*)(dst + dd * NPAD + j0) = o;
      }
    }
  } else {
    // mwp[n][i][lm][16]: lane's 14 jf values contiguous; 0.125 folded in
    int e = (bb - 1024) * 256 + t;          // < 12*256*16
    int n = e >> 12;
    int rem = e & 4095;
    int i = rem >> 4, lm = rem & 15;
    float p0 = mproj[n], p1 = mproj[NHEAD + n], p2 = mproj[2 * NHEAD + n];
    float vals[16];
#pragma unroll
    for (int jf = 0; jf < 16; ++jf) vals[jf] = 0.f;
    if (i < NTOK) {
#pragma unroll
      for (int jf = 0; jf < 14; ++jf) {
        int col = jf * 16 + lm;
        if (col < NTOK) {
          const float* mp = masks + ((size_t)i * NTOK + col) * 3;
          vals[jf] = 0.125f * (mp[0] * p0 + mp[1] * p1 + mp[2] * p2);
        }
      }
    }
    float* dst = mwp + (size_t)e * 16;
#pragma unroll
    for (int q = 0; q < 4; ++q) {
      float4 o = make_float4(vals[q * 4], vals[q * 4 + 1], vals[q * 4 + 2], vals[q * 4 + 3]);
      *(float4*)(dst + q * 4) = o;
    }
  }
}

// ---------- fused score(once) + 6x(mask+softmax+PV) per (i-tile, b, g) ------
__global__ __launch_bounds__(256, 2)
void attn_fused_kernel(const short* __restrict__ qp, const short* __restrict__ kp,
                       const short* __restrict__ vT, const float* __restrict__ mwp,
                       short* __restrict__ vec_b) {
  const int it = blockIdx.x, b = blockIdx.y, g = blockIdx.z;
  __shared__ short Ks[NPAD * 64];       // 28672 B, chunk-swizzled rows
  __shared__ short Pt[64 * 256];        // 32768 B, chunk^(row&7) swizzle
  __shared__ float rsb[64];
  const int t = threadIdx.x, w = t >> 6, l = t & 63;
  const int lm = l & 15, lh = l >> 4, l7 = l & 7;

  const short* qg = qp + ((size_t)b * GHEAD + g) * NPAD * 64;
  const short* kg = kp + ((size_t)b * GHEAD + g) * NPAD * 64;

#pragma unroll
  for (int s = 0; s < 7; ++s)
    gld16(Ks + s * 2048 + t * 8, kg + s * 2048 + t * 8);
  int qrow = it * 64 + w * 16 + lm;
  if (qrow > NPAD - 1) qrow = NPAD - 1;
  s16x8 a0 = *(const s16x8*)(qg + qrow * 64 + lh * 8);
  s16x8 a1 = *(const s16x8*)(qg + qrow * 64 + 32 + lh * 8);
  __syncthreads();

  // ---- score ONCE: 16 rows x 224 cols per wave, kept in registers ----
  f32x4 acc[14] = {};
#pragma unroll
  for (int jf = 0; jf < 14; ++jf) {
    s16x8 kf0 = *(const s16x8*)((const char*)Ks + (jf * 16 + lm) * 128 + ((lh ^ l7) << 4));
    s16x8 kf1 = *(const s16x8*)((const char*)Ks + (jf * 16 + lm) * 128 + (((4 + lh) ^ l7) << 4));
    acc[jf] = __builtin_amdgcn_mfma_f32_16x16x32_bf16(a0, kf0, acc[jf], 0, 0, 0);
    acc[jf] = __builtin_amdgcn_mfma_f32_16x16x32_bf16(a1, kf1, acc[jf], 0, 0, 0);
  }

  for (int hh = 0; hh < HRATIO; ++hh) {
    const int n = g * HRATIO + hh;
    const short* vg = vT + ((size_t)b * NHEAD + n) * 64 * NPAD;
    s16x8 vf[7];
#pragma unroll
    for (int ks = 0; ks < 7; ++ks)
      vf[ks] = *(const s16x8*)(vg + (w * 16 + lm) * NPAD + ks * 32 + lh * 8);

    // ---- mask-mix + no-max softmax (shift-invariant; logits bounded) ----
#pragma unroll
    for (int r = 0; r < 4; ++r) {
      const int row = w * 16 + lh * 4 + r;
      const int i = it * 64 + row;
      const float* mr = mwp + (((size_t)n * 256 + i) * 16 + lm) * 16;
      f32x4 mv0 = *(const f32x4*)(mr);
      f32x4 mv1 = *(const f32x4*)(mr + 4);
      f32x4 mv2 = *(const f32x4*)(mr + 8);
      f32x4 mv3 = *(const f32x4*)(mr + 12);
      float sum = 0.f;
#pragma unroll
      for (int jf = 0; jf < 13; ++jf) {
        float mwv = (jf < 4) ? mv0[jf] : (jf < 8) ? mv1[jf - 4]
                  : (jf < 12) ? mv2[jf - 8] : mv3[jf - 12];
        float pe = __expf(acc[jf][r] * mwv);
        if (jf == 12 && lm >= 5) pe = 0.f;   // cols >= 197
        sum += pe;
        int byteoff = row * 512 + (((2 * jf + (lm >> 3)) ^ (row & 7)) << 4) + (lm & 7) * 2;
        *(short*)((char*)Pt + byteoff) = f2bf(pe);
      }
      {  // jf = 13: cols 208-223 invalid -> zeros
        int byteoff = row * 512 + (((26 + (lm >> 3)) ^ (row & 7)) << 4) + (lm & 7) * 2;
        *(short*)((char*)Pt + byteoff) = 0;
      }
#pragma unroll
      for (int off = 8; off; off >>= 1) sum += __shfl_xor(sum, off);
      if (lm == 0) rsb[row] = 1.f / sum;
    }
    __syncthreads();

    // ---- PV: wave w computes out dims w*16..+15 for all 64 rows ----
    __builtin_amdgcn_s_setprio(1);
    f32x4 oacc[4] = {};
#pragma unroll
    for (int fi = 0; fi < 4; ++fi)
#pragma unroll
      for (int ks = 0; ks < 7; ++ks) {
        s16x8 pa = *(const s16x8*)((const char*)Pt + (fi * 16 + lm) * 512 +
                                   (((ks * 4 + lh) ^ l7) << 4));
        oacc[fi] = __builtin_amdgcn_mfma_f32_16x16x32_bf16(pa, vf[ks], oacc[fi], 0, 0, 0);
      }
    __builtin_amdgcn_s_setprio(0);
#pragma unroll
    for (int fi = 0; fi < 4; ++fi)
#pragma unroll
      for (int r = 0; r < 4; ++r) {
        int ia = it * 64 + fi * 16 + lh * 4 + r;
        if (ia < NTOK) {
          float rsv = rsb[fi * 16 + lh * 4 + r];
          vec_b[((size_t)ia * BATCH + b) * DMODEL + n * 64 + w * 16 + lm] =
              f2bf(oacc[fi][r] * rsv);
        }
      }
    __syncthreads();
  }
}

// ---------- residual + LayerNorm: out = LN(h + proj_b) ----------
__global__ __launch_bounds__(256)
void ln_kernel(const float* __restrict__ h, const short* __restrict__ proj_b,
               float* __restrict__ out, const float* __restrict__ gamma,
               const float* __restrict__ beta) {
  const int m = blockIdx.x;
  const float* hrow = h + (size_t)m * DMODEL;
  const short* prow = proj_b + (size_t)m * DMODEL;
  float* orow = out + (size_t)m * DMODEL;
  const int tid = threadIdx.x;
  float v0 = hrow[tid] + bf2f(prow[tid]);
  float v1 = hrow[tid + 256] + bf2f(prow[tid + 256]);
  float v2 = hrow[tid + 512] + bf2f(prow[tid + 512]);
  float s = v0 + v1 + v2;
  float sq = v0 * v0 + v1 * v1 + v2 * v2;
#pragma unroll
  for (int off = 32; off; off >>= 1) {
    s += __shfl_xor(s, off);
    sq += __shfl_xor(sq, off);
  }
  __shared__ float ss[4], ssq[4];
  const int w = tid >> 6, lane = tid & 63;
  if (lane == 0) { ss[w] = s; ssq[w] = sq; }
  __syncthreads();
  s = ss[0] + ss[1] + ss[2] + ss[3];
  sq = ssq[0] + ssq[1] + ssq[2] + ssq[3];
  const float inv = 1.0f / (float)DMODEL;
  float mu = s * inv;
  float var = sq * inv - mu * mu;
  float rstd = rsqrtf(var + LNEPS);
  orow[tid] = gamma[tid] * (v0 - mu) * rstd + beta[tid];
  orow[tid + 256] = gamma[tid + 256] * (v1 - mu) * rstd + beta[tid + 256];
  orow[tid + 512] = gamma[tid + 512] * (v2 - mu) * rstd + beta[tid + 512];
}

extern "C" void kernel_launch(void* const* d_in, const int* in_sizes, int n_in,
                              void* d_out, int out_size, void* d_ws, size_t ws_size,
                              hipStream_t stream) {
  const float* h     = (const float*)d_in[0];
  const float* masks = (const float*)d_in[1];
  const float* Wq    = (const float*)d_in[2];
  const float* Wk    = (const float*)d_in[3];
  const float* Wv    = (const float*)d_in[4];
  const float* Wo    = (const float*)d_in[5];
  const float* mproj = (const float*)d_in[6];
  const float* gamma = (const float*)d_in[7];
  const float* beta  = (const float*)d_in[8];
  float* out = (float*)d_out;

  char* ws = (char*)d_ws;
  size_t o = 0;
  auto alloc = [&](size_t bytes) { size_t r = o; o += (bytes + 255) & ~(size_t)255; return r; };
  short* hb    = (short*)(ws + alloc((size_t)MPAD * DMODEL * 2));   // aliased: vec_b
  short* Cb    = (short*)(ws + alloc((size_t)MPAD * 1024 * 2));     // aliased: proj_b
  short* Wqkvb = (short*)(ws + alloc((size_t)1024 * DMODEL * 2));
  short* Wob   = (short*)(ws + alloc((size_t)DMODEL * DMODEL * 2));
  short* qp    = (short*)(ws + alloc((size_t)BATCH * GHEAD * NPAD * DHEAD * 2));
  short* kp    = (short*)(ws + alloc((size_t)BATCH * GHEAD * NPAD * DHEAD * 2));
  short* vT    = (short*)(ws + alloc((size_t)BATCH * NHEAD * DHEAD * NPAD * 2));
  float* mwp   = (float*)(ws + alloc((size_t)NHEAD * 256 * 16 * 16 * 4));
  short* vec_b = hb;   // hb dead after QKV gemm
  short* proj_b = Cb;  // Cb dead after packall

  prep_kernel<<<NB_H + NB_QKV + NB_WO, 256, 0, stream>>>(h, Wq, Wk, Wv, Wo, hb, Wqkvb, Wob);
  gemm_bt_kernel<<<dim3(1024 / 128, MPAD / 128), 256, 0, stream>>>(
      hb, Wqkvb, Cb, MROWS, DMODEL, 1024);
  packall_kernel<<<1216, 256, 0, stream>>>(Cb, masks, mproj, qp, kp, vT, mwp);
  attn_fused_kernel<<<dim3(4, BATCH, GHEAD), 256, 0, stream>>>(qp, kp, vT, mwp, vec_b);
  gemm_bt_kernel<<<dim3(DMODEL / 128, MPAD / 128), 256, 0, stream>>>(
      vec_b, Wob, proj_b, MROWS, DMODEL, DMODEL);
  ln_kernel<<<MROWS, 256, 0, stream>>>(h, proj_b, out, gamma, beta);
}

// Round 8
// 144.139 us; speedup vs baseline: 1.0648x; 1.0648x over previous
//
#include <hip/hip_runtime.h>
#include <hip/hip_bf16.h>
#include <stdint.h>

#define NTOK 197
#define NPAD 224
#define BATCH 64
#define DMODEL 768
#define NHEAD 12
#define GHEAD 2
#define HRATIO 6
#define DHEAD 64
#define QKDIM 128
#define LNEPS 1e-5f
#define MROWS (NTOK * BATCH)   /* 12608 */
#define MPAD 12672             /* 99 * 128 */
#define NKC 24                 /* K/32 = 768/32 */
#define NBAND 99               /* MPAD/128 */

using f32x4 = __attribute__((ext_vector_type(4))) float;
using s16x8 = __attribute__((ext_vector_type(8))) short;
using s16x4 = __attribute__((ext_vector_type(4))) short;

__device__ __forceinline__ short f2bf(float f) {
  unsigned int x = __float_as_uint(f);
  return (short)((x + 0x7fffu + ((x >> 16) & 1u)) >> 16);
}

__device__ __forceinline__ float bf2f(short s) {
  return __uint_as_float((unsigned)(unsigned short)s << 16);
}

__device__ __forceinline__ void gld16(void* lds, const void* g) {
  __builtin_amdgcn_global_load_lds(
      (const __attribute__((address_space(1))) unsigned int*)g,
      (__attribute__((address_space(3))) unsigned int*)lds, 16, 0, 0);
}

// ---------- prep: pack fp32 matrices into bf16 MFMA-fragment layout ----------
// Fragment layout: [band][kc][frag(8)][lane(64)x16B]; lane l holds
// a[band*128 + frag*16 + (l&15)][kc*32 + (l>>4)*8 .. +7].
#define NBH (NBAND * NKC)   /* 2376 h blocks */
#define NBQ (8 * NKC)       /* 192 qkv blocks */
#define NBW (6 * NKC)       /* 144 wo blocks */
__global__ __launch_bounds__(256)
void prep_kernel(const float* __restrict__ h, const float* __restrict__ Wq,
                 const float* __restrict__ Wk, const float* __restrict__ Wv,
                 const float* __restrict__ Wo, short* __restrict__ hf,
                 short* __restrict__ Wqkvf, short* __restrict__ Wof) {
  const int bb = blockIdx.x, t = threadIdx.x;
  int band, kc, which;
  if (bb < NBH) { which = 0; band = bb / NKC; kc = bb - band * NKC; }
  else if (bb < NBH + NBQ) { int i = bb - NBH; which = 1; band = i / NKC; kc = i - band * NKC; }
  else { int i = bb - NBH - NBQ; which = 2; band = i / NKC; kc = i - band * NKC; }
  short* dstS = (which == 0 ? hf : which == 1 ? Wqkvf : Wof) +
                ((size_t)(band * NKC + kc) * 8) * 512;
#pragma unroll
  for (int uu = 0; uu < 2; ++uu) {
    int u = t + uu * 256;                 // 0..511
    int frag = u >> 6, l = u & 63;
    int rl = frag * 16 + (l & 15);        // row within band
    int k0 = kc * 32 + ((l >> 4) & 3) * 8;
    float4 a = {0, 0, 0, 0}, c = {0, 0, 0, 0};
    if (which == 0) {
      int row = band * 128 + rl;
      if (row < MROWS) {
        const float* p = h + (size_t)row * DMODEL + k0;
        a = *(const float4*)p; c = *(const float4*)(p + 4);
      }
    } else if (which == 1) {
      int row = band * 128 + rl;          // 0..1023 in [Wq;Wk;Wv]
      const float* src = (row < 128) ? Wq + (size_t)row * DMODEL
                       : (row < 256) ? Wk + (size_t)(row - 128) * DMODEL
                                     : Wv + (size_t)(row - 256) * DMODEL;
      a = *(const float4*)(src + k0); c = *(const float4*)(src + k0 + 4);
    } else {
      const float* p = Wo + (size_t)(band * 128 + rl) * DMODEL + k0;
      a = *(const float4*)p; c = *(const float4*)(p + 4);
    }
    s16x8 o;
    o[0] = f2bf(a.x); o[1] = f2bf(a.y); o[2] = f2bf(a.z); o[3] = f2bf(a.w);
    o[4] = f2bf(c.x); o[5] = f2bf(c.y); o[6] = f2bf(c.z); o[7] = f2bf(c.w);
    *(s16x8*)(dstS + (size_t)u * 8) = o;
  }
}

// ---------- bf16 NT GEMM, fragment-direct (no LDS, no barriers) ----------
// Af [nband][NKC][8][64x16B], Bf [ncband][NKC][8][64x16B], C row-major bf16.
__global__ __launch_bounds__(256)
void gemm_frag_kernel(const short* __restrict__ Af, const short* __restrict__ Bf,
                      short* __restrict__ Cout, int M, int NC) {
  const int tid = threadIdx.x;
  // XCD-bijective swizzle (m204)
  const int nwg = gridDim.x * gridDim.y;
  const int orig = blockIdx.y * gridDim.x + blockIdx.x;
  const int qq = nwg >> 3, rr = nwg & 7;
  const int xcd = orig & 7, sidx = orig >> 3;
  const int wg = (xcd < rr ? xcd * (qq + 1) : rr * (qq + 1) + (xcd - rr) * qq) + sidx;
  const int cb = wg % gridDim.x;          // col band (128 cols)
  const int rb = wg / gridDim.x;          // row band (128 rows)

  const int w = tid >> 6, l = tid & 63;
  const int wr = w >> 1, wc = w & 1;
  const int lm = l & 15, lh = l >> 4;

  const short* pa = Af + ((size_t)(rb * NKC) * 8 + wr * 4) * 512 + l * 8;
  const short* pb = Bf + ((size_t)(cb * NKC) * 8 + wc * 4) * 512 + l * 8;

  f32x4 acc[4][4] = {};
  s16x8 A0[4], B0[4], A1[4], B1[4];

#define LOADF(Ar, Br, kc)                                   \
  do {                                                      \
    const short* qa = pa + (size_t)(kc) * 4096;             \
    const short* qb = pb + (size_t)(kc) * 4096;             \
    Ar[0] = *(const s16x8*)(qa);                            \
    Ar[1] = *(const s16x8*)(qa + 512);                      \
    Ar[2] = *(const s16x8*)(qa + 1024);                     \
    Ar[3] = *(const s16x8*)(qa + 1536);                     \
    Br[0] = *(const s16x8*)(qb);                            \
    Br[1] = *(const s16x8*)(qb + 512);                      \
    Br[2] = *(const s16x8*)(qb + 1024);                     \
    Br[3] = *(const s16x8*)(qb + 1536);                     \
  } while (0)

#define MM(Ar, Br)                                                             \
  do {                                                                         \
    _Pragma("unroll") for (int m = 0; m < 4; ++m)                              \
      _Pragma("unroll") for (int n = 0; n < 4; ++n)                            \
        acc[m][n] = __builtin_amdgcn_mfma_f32_16x16x32_bf16(Ar[m], Br[n],      \
                                                            acc[m][n], 0, 0, 0);\
  } while (0)

  LOADF(A0, B0, 0);
#pragma unroll
  for (int kc = 0; kc < NKC; kc += 2) {
    LOADF(A1, B1, kc + 1);          // kc+1 <= 23 always
    MM(A0, B0);
    if (kc + 2 < NKC) LOADF(A0, B0, kc + 2);
    MM(A1, B1);
  }
#undef LOADF
#undef MM

#pragma unroll
  for (int m = 0; m < 4; ++m) {
#pragma unroll
    for (int r = 0; r < 4; ++r) {
      int row = rb * 128 + wr * 64 + m * 16 + lh * 4 + r;
      if (row < M) {
#pragma unroll
        for (int n = 0; n < 4; ++n) {
          int col = cb * 128 + wc * 64 + n * 16 + lm;
          Cout[(size_t)row * NC + col] = f2bf(acc[m][n][r]);
        }
      }
    }
  }
}

// ---------- fused packs: q(plain)/k(swizzled)/vT(plain) + packed mask mwp ---
__global__ __launch_bounds__(256)
void packall_kernel(const short* __restrict__ Cb, const float* __restrict__ masks,
                    const float* __restrict__ mproj, short* __restrict__ qp,
                    short* __restrict__ kp, short* __restrict__ vT,
                    float* __restrict__ mwp) {
  __shared__ short Vs[NPAD][DHEAD + 1];
  const int bb = blockIdx.x, t = threadIdx.x;
  if (bb < 256) {
    int b = bb >> 2, g = (bb >> 1) & 1, which = bb & 1;
    short* dst = (which ? kp : qp) + ((size_t)b * GHEAD + g) * NPAD * 64;
    int d = t & 63, iofs = t >> 6;
    for (int i0 = 0; i0 < NPAD; i0 += 4) {
      int i = i0 + iofs;
      short v = 0;
      if (i < NTOK)
        v = Cb[(size_t)(i * BATCH + b) * 1024 + which * QKDIM + g * DHEAD + d];
      int dd = which ? ((((d >> 3) ^ (i & 7)) << 3) | (d & 7)) : d;
      dst[i * 64 + dd] = v;
    }
  } else if (bb < 1024) {
    int vv = bb - 256;
    int b = vv / 12, n = vv - b * 12;
    int d = t & 63, iofs = t >> 6;
    for (int i0 = 0; i0 < NPAD; i0 += 4) {
      int i = i0 + iofs;
      short v = 0;
      if (i < NTOK)
        v = Cb[(size_t)(i * BATCH + b) * 1024 + 256 + n * DHEAD + d];
      Vs[i][d] = v;
    }
    __syncthreads();
    short* dst = vT + ((size_t)b * NHEAD + n) * DHEAD * NPAD;
    int sub = t & 63, dr = t >> 6;
    for (int d0 = 0; d0 < DHEAD; d0 += 4) {
      if (sub < 56) {
        int dd = d0 + dr, j0 = sub * 4;
        s16x4 o;
        o[0] = Vs[j0][dd]; o[1] = Vs[j0 + 1][dd];
        o[2] = Vs[j0 + 2][dd]; o[3] = Vs[j0 + 3][dd];
        *(s16x4*)(dst + dd * NPAD + j0) = o;
      }
    }
  } else {
    // mwp[n][i][lm][16]: lane's 14 jf values contiguous; 0.125 folded in
    int e = (bb - 1024) * 256 + t;          // < 12*256*16
    int n = e >> 12;
    int rem = e & 4095;
    int i = rem >> 4, lm = rem & 15;
    float p0 = mproj[n], p1 = mproj[NHEAD + n], p2 = mproj[2 * NHEAD + n];
    float vals[16];
#pragma unroll
    for (int jf = 0; jf < 16; ++jf) vals[jf] = 0.f;
    if (i < NTOK) {
#pragma unroll
      for (int jf = 0; jf < 14; ++jf) {
        int col = jf * 16 + lm;
        if (col < NTOK) {
          const float* mp = masks + ((size_t)i * NTOK + col) * 3;
          vals[jf] = 0.125f * (mp[0] * p0 + mp[1] * p1 + mp[2] * p2);
        }
      }
    }
    float* dst = mwp + (size_t)e * 16;
#pragma unroll
    for (int q = 0; q < 4; ++q) {
      float4 o = make_float4(vals[q * 4], vals[q * 4 + 1], vals[q * 4 + 2], vals[q * 4 + 3]);
      *(float4*)(dst + q * 4) = o;
    }
  }
}

// ---------- fused score(once) + 6x(mask+softmax+PV) per (i-tile, b, g) ------
// Output written in MFMA fragment layout (for the fragment-direct O-proj).
__global__ __launch_bounds__(256, 2)
void attn_fused_kernel(const short* __restrict__ qp, const short* __restrict__ kp,
                       const short* __restrict__ vT, const float* __restrict__ mwp,
                       short* __restrict__ vec_f) {
  const int it = blockIdx.x, b = blockIdx.y, g = blockIdx.z;
  __shared__ short Ks[NPAD * 64];       // 28672 B, chunk-swizzled rows
  __shared__ short Pt[64 * 256];        // 32768 B, chunk^(row&7) swizzle
  __shared__ float rsb[64];
  const int t = threadIdx.x, w = t >> 6, l = t & 63;
  const int lm = l & 15, lh = l >> 4, l7 = l & 7;

  const short* qg = qp + ((size_t)b * GHEAD + g) * NPAD * 64;
  const short* kg = kp + ((size_t)b * GHEAD + g) * NPAD * 64;

#pragma unroll
  for (int s = 0; s < 7; ++s)
    gld16(Ks + s * 2048 + t * 8, kg + s * 2048 + t * 8);
  int qrow = it * 64 + w * 16 + lm;
  if (qrow > NPAD - 1) qrow = NPAD - 1;
  s16x8 a0 = *(const s16x8*)(qg + qrow * 64 + lh * 8);
  s16x8 a1 = *(const s16x8*)(qg + qrow * 64 + 32 + lh * 8);
  __syncthreads();

  // ---- score ONCE: 16 rows x 224 cols per wave, kept in registers ----
  f32x4 acc[14] = {};
#pragma unroll
  for (int jf = 0; jf < 14; ++jf) {
    s16x8 kf0 = *(const s16x8*)((const char*)Ks + (jf * 16 + lm) * 128 + ((lh ^ l7) << 4));
    s16x8 kf1 = *(const s16x8*)((const char*)Ks + (jf * 16 + lm) * 128 + (((4 + lh) ^ l7) << 4));
    acc[jf] = __builtin_amdgcn_mfma_f32_16x16x32_bf16(a0, kf0, acc[jf], 0, 0, 0);
    acc[jf] = __builtin_amdgcn_mfma_f32_16x16x32_bf16(a1, kf1, acc[jf], 0, 0, 0);
  }

  const int b4 = b >> 4;
  const int lofs = ((((w & 1) << 1) + (lm >> 3)) * 16 + (b & 15)) * 8 + (lm & 7);

  for (int hh = 0; hh < HRATIO; ++hh) {
    const int n = g * HRATIO + hh;
    const short* vg = vT + ((size_t)b * NHEAD + n) * 64 * NPAD;
    s16x8 vf[7];
#pragma unroll
    for (int ks = 0; ks < 7; ++ks)
      vf[ks] = *(const s16x8*)(vg + (w * 16 + lm) * NPAD + ks * 32 + lh * 8);

    // ---- mask-mix + no-max softmax (shift-invariant; logits bounded) ----
#pragma unroll
    for (int r = 0; r < 4; ++r) {
      const int row = w * 16 + lh * 4 + r;
      const int i = it * 64 + row;
      const float* mr = mwp + (((size_t)n * 256 + i) * 16 + lm) * 16;
      f32x4 mv0 = *(const f32x4*)(mr);
      f32x4 mv1 = *(const f32x4*)(mr + 4);
      f32x4 mv2 = *(const f32x4*)(mr + 8);
      f32x4 mv3 = *(const f32x4*)(mr + 12);
      float sum = 0.f;
#pragma unroll
      for (int jf = 0; jf < 13; ++jf) {
        float mwv = (jf < 4) ? mv0[jf] : (jf < 8) ? mv1[jf - 4]
                  : (jf < 12) ? mv2[jf - 8] : mv3[jf - 12];
        float pe = __expf(acc[jf][r] * mwv);
        if (jf == 12 && lm >= 5) pe = 0.f;   // cols >= 197
        sum += pe;
        int byteoff = row * 512 + (((2 * jf + (lm >> 3)) ^ (row & 7)) << 4) + (lm & 7) * 2;
        *(short*)((char*)Pt + byteoff) = f2bf(pe);
      }
      {  // jf = 13: cols 208-223 invalid -> zeros
        int byteoff = row * 512 + (((26 + (lm >> 3)) ^ (row & 7)) << 4) + (lm & 7) * 2;
        *(short*)((char*)Pt + byteoff) = 0;
      }
#pragma unroll
      for (int off = 8; off; off >>= 1) sum += __shfl_xor(sum, off);
      if (lm == 0) rsb[row] = 1.f / sum;
    }
    __syncthreads();

    // ---- PV: wave w computes out dims w*16..+15 for all 64 rows ----
    __builtin_amdgcn_s_setprio(1);
    f32x4 oacc[4] = {};
#pragma unroll
    for (int fi = 0; fi < 4; ++fi)
#pragma unroll
      for (int ks = 0; ks < 7; ++ks) {
        s16x8 pa = *(const s16x8*)((const char*)Pt + (fi * 16 + lm) * 512 +
                                   (((ks * 4 + lh) ^ l7) << 4));
        oacc[fi] = __builtin_amdgcn_mfma_f32_16x16x32_bf16(pa, vf[ks], oacc[fi], 0, 0, 0);
      }
    __builtin_amdgcn_s_setprio(0);
    // store into fragment layout: col = n*64 + w*16 + lm, row = ia*64 + b
    const int kcH = n * 2 + (w >> 1);
#pragma unroll
    for (int fi = 0; fi < 4; ++fi)
#pragma unroll
      for (int r = 0; r < 4; ++r) {
        int ia = it * 64 + fi * 16 + lh * 4 + r;
        if (ia < NTOK) {
          float rsv = rsb[fi * 16 + lh * 4 + r];
          int fragidx = ((it * 32 + fi * 8 + lh * 2 + (r >> 1)) * NKC + kcH) * 8 +
                        ((r & 1) << 2) + b4;
          vec_f[(size_t)fragidx * 512 + lofs] = f2bf(oacc[fi][r] * rsv);
        }
      }
    __syncthreads();
  }
}

// ---------- residual + LayerNorm: out = LN(h + proj_b) ----------
__global__ __launch_bounds__(256)
void ln_kernel(const float* __restrict__ h, const short* __restrict__ proj_b,
               float* __restrict__ out, const float* __restrict__ gamma,
               const float* __restrict__ beta) {
  const int m = blockIdx.x;
  const float* hrow = h + (size_t)m * DMODEL;
  const short* prow = proj_b + (size_t)m * DMODEL;
  float* orow = out + (size_t)m * DMODEL;
  const int tid = threadIdx.x;
  float v0 = hrow[tid] + bf2f(prow[tid]);
  float v1 = hrow[tid + 256] + bf2f(prow[tid + 256]);
  float v2 = hrow[tid + 512] + bf2f(prow[tid + 512]);
  float s = v0 + v1 + v2;
  float sq = v0 * v0 + v1 * v1 + v2 * v2;
#pragma unroll
  for (int off = 32; off; off >>= 1) {
    s += __shfl_xor(s, off);
    sq += __shfl_xor(sq, off);
  }
  __shared__ float ss[4], ssq[4];
  const int w = tid >> 6, lane = tid & 63;
  if (lane == 0) { ss[w] = s; ssq[w] = sq; }
  __syncthreads();
  s = ss[0] + ss[1] + ss[2] + ss[3];
  sq = ssq[0] + ssq[1] + ssq[2] + ssq[3];
  const float inv = 1.0f / (float)DMODEL;
  float mu = s * inv;
  float var = sq * inv - mu * mu;
  float rstd = rsqrtf(var + LNEPS);
  orow[tid] = gamma[tid] * (v0 - mu) * rstd + beta[tid];
  orow[tid + 256] = gamma[tid + 256] * (v1 - mu) * rstd + beta[tid + 256];
  orow[tid + 512] = gamma[tid + 512] * (v2 - mu) * rstd + beta[tid + 512];
}

extern "C" void kernel_launch(void* const* d_in, const int* in_sizes, int n_in,
                              void* d_out, int out_size, void* d_ws, size_t ws_size,
                              hipStream_t stream) {
  const float* h     = (const float*)d_in[0];
  const float* masks = (const float*)d_in[1];
  const float* Wq    = (const float*)d_in[2];
  const float* Wk    = (const float*)d_in[3];
  const float* Wv    = (const float*)d_in[4];
  const float* Wo    = (const float*)d_in[5];
  const float* mproj = (const float*)d_in[6];
  const float* gamma = (const float*)d_in[7];
  const float* beta  = (const float*)d_in[8];
  float* out = (float*)d_out;

  char* ws = (char*)d_ws;
  size_t o = 0;
  auto alloc = [&](size_t bytes) { size_t r = o; o += (bytes + 255) & ~(size_t)255; return r; };
  short* hf    = (short*)(ws + alloc((size_t)MPAD * DMODEL * 2));   // aliased: vec_f
  short* Cb    = (short*)(ws + alloc((size_t)MPAD * 1024 * 2));     // aliased: proj_b
  short* Wqkvf = (short*)(ws + alloc((size_t)1024 * DMODEL * 2));
  short* Wof   = (short*)(ws + alloc((size_t)DMODEL * DMODEL * 2));
  short* qp    = (short*)(ws + alloc((size_t)BATCH * GHEAD * NPAD * DHEAD * 2));
  short* kp    = (short*)(ws + alloc((size_t)BATCH * GHEAD * NPAD * DHEAD * 2));
  short* vT    = (short*)(ws + alloc((size_t)BATCH * NHEAD * DHEAD * NPAD * 2));
  float* mwp   = (float*)(ws + alloc((size_t)NHEAD * 256 * 16 * 16 * 4));
  short* vec_f = hf;   // hf dead after QKV gemm (beyond-M frags are zeroed by prep)
  short* proj_b = Cb;  // Cb dead after packall

  prep_kernel<<<NBH + NBQ + NBW, 256, 0, stream>>>(h, Wq, Wk, Wv, Wo, hf, Wqkvf, Wof);
  gemm_frag_kernel<<<dim3(8, NBAND), 256, 0, stream>>>(hf, Wqkvf, Cb, MROWS, 1024);
  packall_kernel<<<1216, 256, 0, stream>>>(Cb, masks, mproj, qp, kp, vT, mwp);
  attn_fused_kernel<<<dim3(4, BATCH, GHEAD), 256, 0, stream>>>(qp, kp, vT, mwp, vec_f);
  gemm_frag_kernel<<<dim3(6, NBAND), 256, 0, stream>>>(vec_f, Wof, proj_b, MROWS, DMODEL);
  ln_kernel<<<MROWS, 256, 0, stream>>>(h, proj_b, out, gamma, beta);
}